// Round 1
// baseline (422.386 us; speedup 1.0000x reference)
//
#include <hip/hip_runtime.h>
#include <cstdint>
#include <cstddef>

typedef unsigned short ushort_t;
typedef __attribute__((ext_vector_type(4))) float f32x4;
typedef __attribute__((ext_vector_type(8))) short short8;
typedef __attribute__((ext_vector_type(4))) float float4_t;
typedef __attribute__((ext_vector_type(4))) unsigned short ushort4_t;

#define KD 2048     // inner dim of both GEMMs
#define TT 2048     // sequence length T
#define NH 32       // heads
#define NG 8        // kv groups

__device__ __forceinline__ ushort_t f2bf(float f) {
  union { float f; uint32_t u; } cv; cv.f = f;
  uint32_t u = cv.u;
  return (ushort_t)((u + 0x7FFFu + ((u >> 16) & 1u)) >> 16);
}

__device__ __forceinline__ void gload_lds16(const void* g, void* l) {
  __builtin_amdgcn_global_load_lds(
      (const __attribute__((address_space(1))) unsigned int*)g,
      (__attribute__((address_space(3))) unsigned int*)l, 16, 0, 0);
}

// ---------------- x f32 -> bf16 ----------------
__global__ __launch_bounds__(256) void cvt_x_kernel(const float* __restrict__ src,
                                                    ushort_t* __restrict__ dst) {
  int i = (blockIdx.x * 256 + threadIdx.x) * 4;
  float4_t v = *(const float4_t*)(src + i);
  ushort4_t o;
  o[0] = f2bf(v[0]); o[1] = f2bf(v[1]); o[2] = f2bf(v[2]); o[3] = f2bf(v[3]);
  *(ushort4_t*)(dst + i) = o;
}

// ---------------- W f32 [K][Nc] -> bf16 [Nc][K] (transposed) ----------------
__global__ __launch_bounds__(256) void cvt_transpose_kernel(const float* __restrict__ src,
                                                            ushort_t* __restrict__ dst,
                                                            int Nc) {
  __shared__ float tile[32][33];
  int tx = threadIdx.x, ty = threadIdx.y;
  int c0 = blockIdx.x * 32, r0 = blockIdx.y * 32;
#pragma unroll
  for (int i = 0; i < 4; i++)
    tile[ty + i * 8][tx] = src[(size_t)(r0 + ty + i * 8) * Nc + c0 + tx];
  __syncthreads();
#pragma unroll
  for (int i = 0; i < 4; i++)
    dst[(size_t)(c0 + ty + i * 8) * KD + r0 + tx] = f2bf(tile[tx][ty + i * 8]);
}

// ---------------- GEMM: C[M][N] = A[M][K] * Bt[N][K]^T, bf16 in, f32 acc ----
// MODE 0: QKV + RoPE epilogue. MODE 1: plain f32 output epilogue.
template <int MODE>
__global__ __launch_bounds__(256) void gemm_kernel(
    const ushort_t* __restrict__ A, const ushort_t* __restrict__ Bt,
    const float* __restrict__ cosT, const float* __restrict__ sinT,
    ushort_t* __restrict__ q_ws, ushort_t* __restrict__ k_ws,
    ushort_t* __restrict__ vt_ws, float* __restrict__ kcache,
    float* __restrict__ vcache, float* __restrict__ outF) {
  __shared__ ushort_t sA[128 * 64];
  __shared__ ushort_t sB[128 * 64];
  const int tid = threadIdx.x;
  const int lane = tid & 63;
  const int w = tid >> 6;
  const int wr = w >> 1, wc = w & 1;
  const int rowBase = blockIdx.y * 128;
  const int colBase = blockIdx.x * 128;

  // staging: 1024 16B-chunks per 128x64 tile; chunk p -> (row=p>>3, physchunk=p&7)
  // LDS dest is linear (global_load_lds), so the SOURCE is pre-swizzled:
  // phys chunk cph holds logical chunk cph ^ (row&7).
  const ushort_t* aSrc[4];
  const ushort_t* bSrc[4];
  int ldsOff[4];
#pragma unroll
  for (int it = 0; it < 4; ++it) {
    int p = it * 256 + tid;
    int r = p >> 3, cph = p & 7;
    int clog = cph ^ (r & 7);
    aSrc[it] = A + (size_t)(rowBase + r) * KD + clog * 8;
    bSrc[it] = Bt + (size_t)(colBase + r) * KD + clog * 8;
    ldsOff[it] = (it * 256 + (tid & ~63)) * 8;  // wave-uniform chunk base
  }

  const f32x4 zero4 = {0.f, 0.f, 0.f, 0.f};
  f32x4 acc[4][4];
#pragma unroll
  for (int i = 0; i < 4; i++)
#pragma unroll
    for (int j = 0; j < 4; j++) acc[i][j] = zero4;

  for (int kt = 0; kt < KD; kt += 64) {
#pragma unroll
    for (int it = 0; it < 4; ++it) {
      gload_lds16(aSrc[it] + kt, sA + ldsOff[it]);
      gload_lds16(bSrc[it] + kt, sB + ldsOff[it]);
    }
    asm volatile("s_waitcnt vmcnt(0)" ::: "memory");
    __syncthreads();
#pragma unroll
    for (int ks = 0; ks < 2; ++ks) {
      short8 af[4], bfr[4];
#pragma unroll
      for (int mi = 0; mi < 4; ++mi) {
        int r = wr * 64 + mi * 16 + (lane & 15);
        af[mi] = *(const short8*)(sA + r * 64 + (((ks * 4 + (lane >> 4)) ^ (r & 7)) * 8));
      }
#pragma unroll
      for (int ni = 0; ni < 4; ++ni) {
        int n = wc * 64 + ni * 16 + (lane & 15);
        bfr[ni] = *(const short8*)(sB + n * 64 + (((ks * 4 + (lane >> 4)) ^ (n & 7)) * 8));
      }
#pragma unroll
      for (int mi = 0; mi < 4; ++mi)
#pragma unroll
        for (int ni = 0; ni < 4; ++ni)
          acc[mi][ni] = __builtin_amdgcn_mfma_f32_16x16x32_bf16(af[mi], bfr[ni],
                                                                acc[mi][ni], 0, 0, 0);
    }
    __syncthreads();
  }

  // epilogue: C/D layout col=lane&15, row=(lane>>4)*4+j
#pragma unroll
  for (int mi = 0; mi < 4; ++mi)
#pragma unroll
    for (int ni = 0; ni < 4; ++ni) {
      int cg = colBase + wc * 64 + ni * 16 + (lane & 15);
      int rg0 = rowBase + wr * 64 + mi * 16 + ((lane >> 4) * 4);
      f32x4 v4 = acc[mi][ni];
#pragma unroll
      for (int j = 0; j < 4; ++j) {
        float v = v4[j];
        float pv = __shfl_xor(v, 1);  // paired RoPE column (adjacent lane)
        int row = rg0 + j;
        if constexpr (MODE == 0) {
          int bb = row >> 11, t = row & (TT - 1);
          int d = cg & 63, i2 = d >> 1;
          if (cg < 2048) {  // q
            float cc = cosT[t * 32 + i2], ss = sinT[t * 32 + i2];
            float out = (d & 1) ? (pv * ss + v * cc) : (v * cc - pv * ss);
            int h = cg >> 6;
            q_ws[(((size_t)(bb * NH + h)) * TT + t) * 64 + d] = f2bf(out * 0.125f);
          } else if (cg < 2560) {  // k (roped)
            float cc = cosT[t * 32 + i2], ss = sinT[t * 32 + i2];
            float out = (d & 1) ? (pv * ss + v * cc) : (v * cc - pv * ss);
            int gg = (cg - 2048) >> 6;
            kcache[(((size_t)(bb * TT + t)) * NG + gg) * 64 + d] = out;
            k_ws[(((size_t)(bb * NG + gg)) * TT + t) * 64 + d] = f2bf(out);
          } else {  // v
            int gg = (cg - 2560) >> 6;
            vcache[(((size_t)(bb * TT + t)) * NG + gg) * 64 + d] = v;
            vt_ws[(((size_t)(bb * NG + gg)) * 64 + d) * TT + t] = f2bf(v);
          }
        } else {
          outF[(size_t)row * 2048 + cg] = v;
        }
      }
    }
}

// ---------------- flash attention, causal, GQA ----------------
// grid: (b*H + h)*32 + qt ; block 256 = 4 waves x 16 q-rows
__global__ __launch_bounds__(256) void attn_kernel(const ushort_t* __restrict__ qw,
                                                   const ushort_t* __restrict__ kw,
                                                   const ushort_t* __restrict__ vtw,
                                                   ushort_t* __restrict__ attn) {
  __shared__ ushort_t sK[64 * 64];
  __shared__ ushort_t sV[64 * 64];        // V^T tile: [d][key]
  __shared__ ushort_t sP[4][16 * 64];     // per-wave P roundtrip
  const int tid = threadIdx.x;
  const int lane = tid & 63;
  const int w = tid >> 6;
  const int blk = blockIdx.x;
  const int qt = blk & 31;
  const int h = (blk >> 5) & 31;
  const int b = blk >> 10;
  const int g = h >> 2;  // rep = H/G = 4, repeat_interleave
  const ushort_t* qbase = qw + (size_t)(b * NH + h) * TT * 64;
  const ushort_t* kbase = kw + (size_t)(b * NG + g) * TT * 64;
  const ushort_t* vtbase = vtw + (size_t)(b * NG + g) * 64 * TT;
  const int qr0 = qt * 64 + w * 16;

  short8 aq[2];
#pragma unroll
  for (int ds = 0; ds < 2; ++ds)
    aq[ds] = *(const short8*)(qbase + (size_t)(qr0 + (lane & 15)) * 64 + ds * 32 +
                              (lane >> 4) * 8);

  const f32x4 zero4 = {0.f, 0.f, 0.f, 0.f};
  f32x4 o[4];
#pragma unroll
  for (int i = 0; i < 4; i++) o[i] = zero4;
  float mrow[4] = {-1e30f, -1e30f, -1e30f, -1e30f};
  float lrow[4] = {0.f, 0.f, 0.f, 0.f};

  const int ktiles = qt + 1;
  for (int kt = 0; kt < ktiles; ++kt) {
    const int k0 = kt * 64;
    short8 kreg[2], vreg[2];
    int prow[2], pc[2];
#pragma unroll
    for (int i = 0; i < 2; ++i) {
      int p = i * 256 + tid;
      prow[i] = p >> 3; pc[i] = p & 7;
      kreg[i] = *(const short8*)(kbase + (size_t)(k0 + prow[i]) * 64 + pc[i] * 8);
      vreg[i] = *(const short8*)(vtbase + (size_t)prow[i] * TT + k0 + pc[i] * 8);
    }
    __syncthreads();  // previous tile's compute done
#pragma unroll
    for (int i = 0; i < 2; ++i) {
      int sw = (pc[i] ^ (prow[i] & 7)) * 8;
      *(short8*)(sK + prow[i] * 64 + sw) = kreg[i];
      *(short8*)(sV + prow[i] * 64 + sw) = vreg[i];
    }
    __syncthreads();

    // S = Q K^T  (A=Q[16x32d], B=K^T[32d x 16key])
    f32x4 s[4];
#pragma unroll
    for (int f = 0; f < 4; ++f) s[f] = zero4;
#pragma unroll
    for (int ds = 0; ds < 2; ++ds)
#pragma unroll
      for (int f = 0; f < 4; ++f) {
        int key = f * 16 + (lane & 15);
        short8 kb = *(const short8*)(sK + key * 64 +
                                     (((ds * 4 + (lane >> 4)) ^ (key & 7)) * 8));
        s[f] = __builtin_amdgcn_mfma_f32_16x16x32_bf16(aq[ds], kb, s[f], 0, 0, 0);
      }
    if (kt == ktiles - 1) {  // diagonal tile: causal mask
#pragma unroll
      for (int f = 0; f < 4; ++f)
#pragma unroll
        for (int j = 0; j < 4; ++j) {
          int keyg = k0 + f * 16 + (lane & 15);
          int rowg = qr0 + (lane >> 4) * 4 + j;
          if (keyg > rowg) s[f][j] = -1e30f;
        }
    }
    // online softmax (rows live in 16-lane groups)
#pragma unroll
    for (int j = 0; j < 4; ++j) {
      float m0 = fmaxf(fmaxf(s[0][j], s[1][j]), fmaxf(s[2][j], s[3][j]));
      m0 = fmaxf(m0, __shfl_xor(m0, 1));
      m0 = fmaxf(m0, __shfl_xor(m0, 2));
      m0 = fmaxf(m0, __shfl_xor(m0, 4));
      m0 = fmaxf(m0, __shfl_xor(m0, 8));
      float mn = fmaxf(mrow[j], m0);
      float alpha = __expf(mrow[j] - mn);
      mrow[j] = mn;
      lrow[j] *= alpha;
#pragma unroll
      for (int fo = 0; fo < 4; ++fo) o[fo][j] *= alpha;
      float rs = 0.f;
#pragma unroll
      for (int f = 0; f < 4; ++f) {
        float p = __expf(s[f][j] - mn);
        s[f][j] = p;
        rs += p;
      }
      rs += __shfl_xor(rs, 1); rs += __shfl_xor(rs, 2);
      rs += __shfl_xor(rs, 4); rs += __shfl_xor(rs, 8);
      lrow[j] += rs;
    }
    // P -> per-wave LDS (swizzled), then PV
#pragma unroll
    for (int f = 0; f < 4; ++f)
#pragma unroll
      for (int j = 0; j < 4; ++j) {
        int row = (lane >> 4) * 4 + j;
        int key = f * 16 + (lane & 15);
        sP[w][row * 64 + (((key >> 3) ^ (row & 7)) * 8) + (key & 7)] = f2bf(s[f][j]);
      }
#pragma unroll
    for (int ds = 0; ds < 2; ++ds) {
      int pr = lane & 15;
      short8 pa = *(const short8*)(&sP[w][pr * 64 +
                                          (((ds * 4 + (lane >> 4)) ^ (pr & 7)) * 8)]);
#pragma unroll
      for (int fo = 0; fo < 4; ++fo) {
        int vr = fo * 16 + (lane & 15);
        short8 vb = *(const short8*)(sV + vr * 64 +
                                     (((ds * 4 + (lane >> 4)) ^ (vr & 7)) * 8));
        o[fo] = __builtin_amdgcn_mfma_f32_16x16x32_bf16(pa, vb, o[fo], 0, 0, 0);
      }
    }
  }
  // epilogue: attn[b][t][h*64+d] bf16
#pragma unroll
  for (int fo = 0; fo < 4; ++fo)
#pragma unroll
    for (int j = 0; j < 4; ++j) {
      int row = qr0 + (lane >> 4) * 4 + j;
      int col = h * 64 + fo * 16 + (lane & 15);
      attn[((size_t)b * TT + row) * 2048 + col] = f2bf(o[fo][j] / lrow[j]);
    }
}

extern "C" void kernel_launch(void* const* d_in, const int* in_sizes, int n_in,
                              void* d_out, int out_size, void* d_ws, size_t ws_size,
                              hipStream_t stream) {
  (void)in_sizes; (void)n_in; (void)out_size; (void)ws_size;
  const float* x    = (const float*)d_in[0];
  const float* cosT = (const float*)d_in[1];
  const float* sinT = (const float*)d_in[2];
  const float* Wq   = (const float*)d_in[4];
  const float* Wk   = (const float*)d_in[5];
  const float* Wv   = (const float*)d_in[6];
  const float* Wo   = (const float*)d_in[7];

  float* outF   = (float*)d_out;
  float* kcache = outF + (size_t)8388608;             // B*T*C
  float* vcache = kcache + (size_t)2097152;           // B*T*G*D

  uint8_t* ws = (uint8_t*)d_ws;
  ushort_t* x_bf   = (ushort_t*)(ws);                 // 16 MiB
  ushort_t* wqkvT  = (ushort_t*)(ws + 16777216);      // 12 MiB  [3072][2048]
  ushort_t* woT    = (ushort_t*)(ws + 29360128);      // 8 MiB   [2048][2048]
  ushort_t* q_ws   = (ushort_t*)(ws + 37748736);      // 16 MiB  [B][H][T][64]
  ushort_t* k_ws   = (ushort_t*)(ws + 54525952);      // 4 MiB   [B][G][T][64]
  ushort_t* vt_ws  = (ushort_t*)(ws + 58720256);      // 4 MiB   [B][G][64][T]
  ushort_t* attn_ws= (ushort_t*)(ws + 62914560);      // 16 MiB  [B*T][2048]

  cvt_x_kernel<<<8192, 256, 0, stream>>>(x, x_bf);
  cvt_transpose_kernel<<<dim3(64, 64), dim3(32, 8), 0, stream>>>(Wq, wqkvT, 2048);
  cvt_transpose_kernel<<<dim3(16, 64), dim3(32, 8), 0, stream>>>(Wk, wqkvT + (size_t)2048 * KD, 512);
  cvt_transpose_kernel<<<dim3(16, 64), dim3(32, 8), 0, stream>>>(Wv, wqkvT + (size_t)2560 * KD, 512);
  cvt_transpose_kernel<<<dim3(64, 64), dim3(32, 8), 0, stream>>>(Wo, woT, 2048);

  gemm_kernel<0><<<dim3(24, 32), 256, 0, stream>>>(x_bf, wqkvT, cosT, sinT, q_ws,
                                                   k_ws, vt_ws, kcache, vcache, nullptr);
  attn_kernel<<<2048, 256, 0, stream>>>(q_ws, k_ws, vt_ws, attn_ws);
  gemm_kernel<1><<<dim3(16, 32), 256, 0, stream>>>(attn_ws, woT, nullptr, nullptr,
                                                   nullptr, nullptr, nullptr, nullptr,
                                                   nullptr, outF);
}

// Round 2
// 231.782 us; speedup vs baseline: 1.8223x; 1.8223x over previous
//
#include <hip/hip_runtime.h>
#include <cstdint>
#include <cstddef>

typedef unsigned short ushort_t;
typedef __attribute__((ext_vector_type(4))) float f32x4;
typedef __attribute__((ext_vector_type(16))) float f32x16;
typedef __attribute__((ext_vector_type(8))) short short8;
typedef __attribute__((ext_vector_type(4))) float float4_t;
typedef __attribute__((ext_vector_type(4))) unsigned short ushort4_t;
typedef __attribute__((ext_vector_type(2))) unsigned int uint2v;

#define KD 2048     // inner dim of both GEMMs
#define TT 2048     // sequence length T
#define NH 32       // heads
#define NG 8        // kv groups

__device__ __forceinline__ ushort_t f2bf(float f) {
  union { float f; uint32_t u; } cv; cv.f = f;
  uint32_t u = cv.u;
  return (ushort_t)((u + 0x7FFFu + ((u >> 16) & 1u)) >> 16);
}

__device__ __forceinline__ uint32_t cvtpk(float a, float b) {
  uint32_t r;
  asm("v_cvt_pk_bf16_f32 %0, %1, %2" : "=v"(r) : "v"(a), "v"(b));
  return r;
}

__device__ __forceinline__ float exp2fast(float x) {
  float r;
  asm("v_exp_f32 %0, %1" : "=v"(r) : "v"(x));
  return r;
}

__device__ __forceinline__ void gload_lds16(const void* g, void* l) {
  __builtin_amdgcn_global_load_lds(
      (const __attribute__((address_space(1))) unsigned int*)g,
      (__attribute__((address_space(3))) unsigned int*)l, 16, 0, 0);
}

// ---------------- x f32 -> bf16 ----------------
__global__ __launch_bounds__(256) void cvt_x_kernel(const float* __restrict__ src,
                                                    ushort_t* __restrict__ dst) {
  int i = (blockIdx.x * 256 + threadIdx.x) * 4;
  float4_t v = *(const float4_t*)(src + i);
  ushort4_t o;
  o[0] = f2bf(v[0]); o[1] = f2bf(v[1]); o[2] = f2bf(v[2]); o[3] = f2bf(v[3]);
  *(ushort4_t*)(dst + i) = o;
}

// ---------------- W f32 [K][Nc] -> bf16 [Nc][K] (transposed) ----------------
__global__ __launch_bounds__(256) void cvt_transpose_kernel(const float* __restrict__ src,
                                                            ushort_t* __restrict__ dst,
                                                            int Nc) {
  __shared__ float tile[32][33];
  int tx = threadIdx.x, ty = threadIdx.y;
  int c0 = blockIdx.x * 32, r0 = blockIdx.y * 32;
#pragma unroll
  for (int i = 0; i < 4; i++)
    tile[ty + i * 8][tx] = src[(size_t)(r0 + ty + i * 8) * Nc + c0 + tx];
  __syncthreads();
#pragma unroll
  for (int i = 0; i < 4; i++)
    dst[(size_t)(c0 + ty + i * 8) * KD + r0 + tx] = f2bf(tile[tx][ty + i * 8]);
}

// ---------------- GEMM: C[M][N] = A[M][K] * Bt[N][K]^T, bf16 in, f32 acc ----
// MODE 0: QKV + RoPE epilogue. MODE 1: plain f32 output epilogue.
template <int MODE>
__global__ __launch_bounds__(256) void gemm_kernel(
    const ushort_t* __restrict__ A, const ushort_t* __restrict__ Bt,
    const float* __restrict__ cosT, const float* __restrict__ sinT,
    ushort_t* __restrict__ q_ws, ushort_t* __restrict__ k_ws,
    ushort_t* __restrict__ vt_ws, float* __restrict__ kcache,
    float* __restrict__ vcache, float* __restrict__ outF) {
  __shared__ ushort_t sA[128 * 64];
  __shared__ ushort_t sB[128 * 64];
  const int tid = threadIdx.x;
  const int lane = tid & 63;
  const int w = tid >> 6;
  const int wr = w >> 1, wc = w & 1;
  const int rowBase = blockIdx.y * 128;
  const int colBase = blockIdx.x * 128;

  const ushort_t* aSrc[4];
  const ushort_t* bSrc[4];
  int ldsOff[4];
#pragma unroll
  for (int it = 0; it < 4; ++it) {
    int p = it * 256 + tid;
    int r = p >> 3, cph = p & 7;
    int clog = cph ^ (r & 7);
    aSrc[it] = A + (size_t)(rowBase + r) * KD + clog * 8;
    bSrc[it] = Bt + (size_t)(colBase + r) * KD + clog * 8;
    ldsOff[it] = (it * 256 + (tid & ~63)) * 8;
  }

  const f32x4 zero4 = {0.f, 0.f, 0.f, 0.f};
  f32x4 acc[4][4];
#pragma unroll
  for (int i = 0; i < 4; i++)
#pragma unroll
    for (int j = 0; j < 4; j++) acc[i][j] = zero4;

  for (int kt = 0; kt < KD; kt += 64) {
#pragma unroll
    for (int it = 0; it < 4; ++it) {
      gload_lds16(aSrc[it] + kt, sA + ldsOff[it]);
      gload_lds16(bSrc[it] + kt, sB + ldsOff[it]);
    }
    asm volatile("s_waitcnt vmcnt(0)" ::: "memory");
    __syncthreads();
#pragma unroll
    for (int ks = 0; ks < 2; ++ks) {
      short8 af[4], bfr[4];
#pragma unroll
      for (int mi = 0; mi < 4; ++mi) {
        int r = wr * 64 + mi * 16 + (lane & 15);
        af[mi] = *(const short8*)(sA + r * 64 + (((ks * 4 + (lane >> 4)) ^ (r & 7)) * 8));
      }
#pragma unroll
      for (int ni = 0; ni < 4; ++ni) {
        int n = wc * 64 + ni * 16 + (lane & 15);
        bfr[ni] = *(const short8*)(sB + n * 64 + (((ks * 4 + (lane >> 4)) ^ (n & 7)) * 8));
      }
#pragma unroll
      for (int mi = 0; mi < 4; ++mi)
#pragma unroll
        for (int ni = 0; ni < 4; ++ni)
          acc[mi][ni] = __builtin_amdgcn_mfma_f32_16x16x32_bf16(af[mi], bfr[ni],
                                                                acc[mi][ni], 0, 0, 0);
    }
    __syncthreads();
  }

#pragma unroll
  for (int mi = 0; mi < 4; ++mi)
#pragma unroll
    for (int ni = 0; ni < 4; ++ni) {
      int cg = colBase + wc * 64 + ni * 16 + (lane & 15);
      int rg0 = rowBase + wr * 64 + mi * 16 + ((lane >> 4) * 4);
      f32x4 v4 = acc[mi][ni];
#pragma unroll
      for (int j = 0; j < 4; ++j) {
        float v = v4[j];
        float pv = __shfl_xor(v, 1);
        int row = rg0 + j;
        if constexpr (MODE == 0) {
          int bb = row >> 11, t = row & (TT - 1);
          int d = cg & 63, i2 = d >> 1;
          if (cg < 2048) {  // q (scale folds 1/8 and log2(e) for exp2 softmax)
            float cc = cosT[t * 32 + i2], ss = sinT[t * 32 + i2];
            float out = (d & 1) ? (pv * ss + v * cc) : (v * cc - pv * ss);
            int hh = cg >> 6;
            q_ws[(((size_t)(bb * NH + hh)) * TT + t) * 64 + d] = f2bf(out * 0.18033688f);
          } else if (cg < 2560) {  // k (roped)
            float cc = cosT[t * 32 + i2], ss = sinT[t * 32 + i2];
            float out = (d & 1) ? (pv * ss + v * cc) : (v * cc - pv * ss);
            int gg = (cg - 2048) >> 6;
            kcache[(((size_t)(bb * TT + t)) * NG + gg) * 64 + d] = out;
            k_ws[(((size_t)(bb * NG + gg)) * TT + t) * 64 + d] = f2bf(out);
          } else {  // v
            int gg = (cg - 2560) >> 6;
            vcache[(((size_t)(bb * TT + t)) * NG + gg) * 64 + d] = v;
            vt_ws[(((size_t)(bb * NG + gg)) * 64 + d) * TT + t] = f2bf(v);
          }
        } else {
          outF[(size_t)row * 2048 + cg] = v;
        }
      }
    }
}

// ---------------- flash attention v2: swapped 32x32 MFMA, in-register softmax
// grid: 1024 blocks; block = 4 waves x 32 q-rows = 128 q-rows.
// bid -> qt = 15-(bid>>6) (LPT), head packing g-major for XCD L2 locality.
#define PACK(SV, E, OUT)                                        \
  {                                                             \
    uint32_t A0 = cvtpk(SV[8 * E + 0], SV[8 * E + 1]);          \
    uint32_t A1 = cvtpk(SV[8 * E + 2], SV[8 * E + 3]);          \
    uint32_t B0 = cvtpk(SV[8 * E + 4], SV[8 * E + 5]);          \
    uint32_t B1 = cvtpk(SV[8 * E + 6], SV[8 * E + 7]);          \
    asm("v_permlane32_swap_b32 %0, %1" : "+v"(A0), "+v"(B0));   \
    asm("v_permlane32_swap_b32 %0, %1" : "+v"(A1), "+v"(B1));   \
    union { uint32_t u[4]; short8 s8; } UU;                     \
    UU.u[0] = A0; UU.u[1] = A1; UU.u[2] = B0; UU.u[3] = B1;     \
    OUT = UU.s8;                                                \
  }

__global__ __launch_bounds__(256, 4) void attn_kernel(const ushort_t* __restrict__ qw,
                                                      const ushort_t* __restrict__ kw,
                                                      const ushort_t* __restrict__ vtw,
                                                      ushort_t* __restrict__ attn) {
  __shared__ ushort_t sK[2][4096];   // [64 keys][64 d], chunk-swizzled
  __shared__ ushort_t sVT[2][4096];  // [64 d][64 keys], chunk-swizzled
  const int tid = threadIdx.x;
  const int lane = tid & 63;
  const int w = tid >> 6;
  const int hi = lane >> 5;
  const int col = lane & 31;
  const int bid = blockIdx.x;
  const int jj = bid & 63;
  const int rep = jj >> 4;
  const int bg = jj & 15;
  const int b = bg >> 3, g = bg & 7;
  const int h = g * 4 + rep;
  const int qt = 15 - (bid >> 6);
  const int q0w = qt * 128 + w * 32;
  const int qg = q0w + col;
  const int ntiles = 2 * qt + 2;

  const ushort_t* qbase = qw + ((size_t)(b * NH + h) * TT + qg) * 64;
  const ushort_t* kbase = kw + (size_t)(b * NG + g) * TT * 64;
  const ushort_t* vtbase = vtw + (size_t)(b * NG + g) * 64 * TT;

  // Q fragments: B-operand of S^T mfma. lane holds q-row=col, d=dsub*16+hi*8..+8
  short8 qf[4];
#pragma unroll
  for (int dsub = 0; dsub < 4; ++dsub)
    qf[dsub] = *(const short8*)(qbase + dsub * 16 + hi * 8);

  // staging: 512 chunks of 16B per 8KB tile; source pre-swizzled, LDS linear
  const int r0 = tid >> 3;
  const int cl = (tid & 7) ^ (r0 & 7);
  const ushort_t* kS0 = kbase + r0 * 64 + cl * 8;
  const ushort_t* kS1 = kbase + (r0 + 32) * 64 + cl * 8;
  const ushort_t* vS0 = vtbase + (size_t)r0 * TT + cl * 8;
  const ushort_t* vS1 = vtbase + (size_t)(r0 + 32) * TT + cl * 8;
  const int off0 = (tid & ~63) * 8;
  const int off1 = off0 + 2048;

  auto stage = [&](int bb, int k0) {
    gload_lds16(kS0 + (size_t)k0 * 64, &sK[bb][off0]);
    gload_lds16(kS1 + (size_t)k0 * 64, &sK[bb][off1]);
    gload_lds16(vS0 + k0, &sVT[bb][off0]);
    gload_lds16(vS1 + k0, &sVT[bb][off1]);
  };

  f32x16 o0 = {};
  f32x16 o1 = {};
  float m_run = -3.0e38f, l_run = 0.f;

  stage(0, 0);
  asm volatile("s_waitcnt vmcnt(0)" ::: "memory");
  __syncthreads();

  for (int kt = 0; kt < ntiles; ++kt) {
    const int k0 = kt * 64;
    const int buf = kt & 1;
    if (kt + 1 < ntiles) stage(buf ^ 1, k0 + 64);
    if (k0 <= q0w + 31) {
      const ushort_t* K = sK[buf];
      const ushort_t* V = sVT[buf];
      // S^T[key][q] : A = K rows (key=kb*32+col), B = Q^T
      f32x16 s0 = {};
      f32x16 s1 = {};
#pragma unroll
      for (int dsub = 0; dsub < 4; ++dsub) {
        const int ch = dsub * 2 + hi;
        const int sw = ((ch ^ (col & 7)) * 8);
        short8 a0 = *(const short8*)(K + col * 64 + sw);
        short8 a1 = *(const short8*)(K + (32 + col) * 64 + sw);
        s0 = __builtin_amdgcn_mfma_f32_32x32x16_bf16(a0, qf[dsub], s0, 0, 0, 0);
        s1 = __builtin_amdgcn_mfma_f32_32x32x16_bf16(a1, qf[dsub], s1, 0, 0, 0);
      }
      // causal mask (diagonal region only)
      if (k0 + 63 > q0w) {
#pragma unroll
        for (int r = 0; r < 16; ++r) {
          int key5 = (r & 3) + 8 * (r >> 2) + 4 * hi;
          if (k0 + key5 > qg) s0[r] = -3.0e38f;
          if (k0 + 32 + key5 > qg) s1[r] = -3.0e38f;
        }
      }
      // online softmax: row is lane-local (32 values) + partner half
      float tm[16];
#pragma unroll
      for (int r = 0; r < 16; ++r) tm[r] = fmaxf(s0[r], s1[r]);
#pragma unroll
      for (int st = 8; st > 0; st >>= 1)
#pragma unroll
        for (int r = 0; r < 8; ++r)
          if (r < st) tm[r] = fmaxf(tm[r], tm[r + st]);
      float mt = fmaxf(tm[0], __shfl_xor(tm[0], 32));
      float mn = fmaxf(m_run, mt);
      float al = exp2fast(m_run - mn);
      m_run = mn;
      float ts[16];
#pragma unroll
      for (int r = 0; r < 16; ++r) {
        s0[r] = exp2fast(s0[r] - mn);
        s1[r] = exp2fast(s1[r] - mn);
        ts[r] = s0[r] + s1[r];
      }
#pragma unroll
      for (int st = 8; st > 0; st >>= 1)
#pragma unroll
        for (int r = 0; r < 8; ++r)
          if (r < st) ts[r] += ts[r + st];
      float rs = ts[0] + __shfl_xor(ts[0], 32);
      l_run = l_run * al + rs;
#pragma unroll
      for (int r = 0; r < 16; ++r) { o0[r] *= al; o1[r] *= al; }
      // P^T -> B-frags (cvt_pk + permlane32_swap), PV: O^T += V^T * P^T
      short8 pb;
      const int swz = (col & 7);
#define PVMM(KS)                                                            \
  {                                                                         \
    const int ch = KS * 2 + hi;                                             \
    const int so = ((ch ^ swz) * 8);                                        \
    short8 va = *(const short8*)(V + col * 64 + so);                        \
    short8 vb = *(const short8*)(V + (32 + col) * 64 + so);                 \
    o0 = __builtin_amdgcn_mfma_f32_32x32x16_bf16(va, pb, o0, 0, 0, 0);      \
    o1 = __builtin_amdgcn_mfma_f32_32x32x16_bf16(vb, pb, o1, 0, 0, 0);      \
  }
      PACK(s0, 0, pb); PVMM(0)
      PACK(s0, 1, pb); PVMM(1)
      PACK(s1, 0, pb); PVMM(2)
      PACK(s1, 1, pb); PVMM(3)
#undef PVMM
    }
    asm volatile("s_waitcnt vmcnt(0)" ::: "memory");
    __syncthreads();
  }

  // epilogue: O^T regs: q=col, d = dblk*32 + (r&3)+8*(r>>2)+4*hi
  const float inv = 1.f / l_run;
  ushort_t* obase = attn + ((size_t)b * TT + qg) * 2048 + h * 64;
#pragma unroll
  for (int g4 = 0; g4 < 4; ++g4) {
    int d = g4 * 8 + hi * 4;
    uint2v u;
    u[0] = cvtpk(o0[4 * g4 + 0] * inv, o0[4 * g4 + 1] * inv);
    u[1] = cvtpk(o0[4 * g4 + 2] * inv, o0[4 * g4 + 3] * inv);
    *(uint2v*)(obase + d) = u;
    uint2v u2;
    u2[0] = cvtpk(o1[4 * g4 + 0] * inv, o1[4 * g4 + 1] * inv);
    u2[1] = cvtpk(o1[4 * g4 + 2] * inv, o1[4 * g4 + 3] * inv);
    *(uint2v*)(obase + 32 + d) = u2;
  }
}

extern "C" void kernel_launch(void* const* d_in, const int* in_sizes, int n_in,
                              void* d_out, int out_size, void* d_ws, size_t ws_size,
                              hipStream_t stream) {
  (void)in_sizes; (void)n_in; (void)out_size; (void)ws_size;
  const float* x    = (const float*)d_in[0];
  const float* cosT = (const float*)d_in[1];
  const float* sinT = (const float*)d_in[2];
  const float* Wq   = (const float*)d_in[4];
  const float* Wk   = (const float*)d_in[5];
  const float* Wv   = (const float*)d_in[6];
  const float* Wo   = (const float*)d_in[7];

  float* outF   = (float*)d_out;
  float* kcache = outF + (size_t)8388608;             // B*T*C
  float* vcache = kcache + (size_t)2097152;           // B*T*G*D

  uint8_t* ws = (uint8_t*)d_ws;
  ushort_t* x_bf   = (ushort_t*)(ws);                 // 16 MiB
  ushort_t* wqkvT  = (ushort_t*)(ws + 16777216);      // 12 MiB  [3072][2048]
  ushort_t* woT    = (ushort_t*)(ws + 29360128);      // 8 MiB   [2048][2048]
  ushort_t* q_ws   = (ushort_t*)(ws + 37748736);      // 16 MiB  [B][H][T][64]
  ushort_t* k_ws   = (ushort_t*)(ws + 54525952);      // 4 MiB   [B][G][T][64]
  ushort_t* vt_ws  = (ushort_t*)(ws + 58720256);      // 4 MiB   [B][G][64][T]
  ushort_t* attn_ws= (ushort_t*)(ws + 62914560);      // 16 MiB  [B*T][2048]

  cvt_x_kernel<<<8192, 256, 0, stream>>>(x, x_bf);
  cvt_transpose_kernel<<<dim3(64, 64), dim3(32, 8), 0, stream>>>(Wq, wqkvT, 2048);
  cvt_transpose_kernel<<<dim3(16, 64), dim3(32, 8), 0, stream>>>(Wk, wqkvT + (size_t)2048 * KD, 512);
  cvt_transpose_kernel<<<dim3(16, 64), dim3(32, 8), 0, stream>>>(Wv, wqkvT + (size_t)2560 * KD, 512);
  cvt_transpose_kernel<<<dim3(64, 64), dim3(32, 8), 0, stream>>>(Wo, woT, 2048);

  gemm_kernel<0><<<dim3(24, 32), 256, 0, stream>>>(x_bf, wqkvT, cosT, sinT, q_ws,
                                                   k_ws, vt_ws, kcache, vcache, nullptr);
  attn_kernel<<<1024, 256, 0, stream>>>(q_ws, k_ws, vt_ws, attn_ws);
  gemm_kernel<1><<<dim3(16, 32), 256, 0, stream>>>(attn_ws, woT, nullptr, nullptr,
                                                   nullptr, nullptr, nullptr, nullptr,
                                                   nullptr, outF);
}